// Round 11
// baseline (288.196 us; speedup 1.0000x reference)
//
#include <hip/hip_runtime.h>

#define DIM   256
#define BATCH 16
#define NPX   (DIM*DIM)

// all padded global arrays share one layout: [280 rows][284 cols],
// px(gy,gx) at (gy+12, gx+12); zeros outside the image.
#define PR   280
#define PC   284
#define PBS  (PR*PC)
#define NPAD ((size_t)BATCH*PBS)

// LDS: fields only, [2][58][100] = 46.4 KB -> 2 blocks/CU (92.8 KB/CU).
// Block tile = 32 rows x 64 cols, halo 12 -> region 56 x 88 (+2 overreach rows,
// +4-col left pad). Coefficients are NOT staged: read from global (L2 slab).
#define LR 58
#define LC 100

// Collapse the 14 used fd_kernels into one effective 7x7 kernel.
__global__ void prep_eff(const float* __restrict__ fdk,
                         const float* __restrict__ cw,
                         float* __restrict__ eff) {
    int t = threadIdx.x;
    if (t < 49) {
        float s = 0.f;
        #pragma unroll
        for (int c = 1; c < 15; ++c)
            s += fdk[c * 49 + t] * cw[c - 1];
        eff[t] = s;
    }
}

// XCD-aware streaming prologue (unchanged from r10): block i -> batch
// 2(i&7)+((i>>3)&1). Builds 6 identically-padded planes.
__global__ __launch_bounds__(1024) void prologue(
    const float* __restrict__ u1, const float* __restrict__ u0,
    const float* __restrict__ epsr, const float* __restrict__ sigma,
    float* __restrict__ A1, float* __restrict__ A0,
    float* __restrict__ B1, float* __restrict__ B0,
    float* __restrict__ CDp, float* __restrict__ CGp)
{
    const int i = blockIdx.x;
    const int b = 2 * (i & 7) + ((i >> 3) & 1);
    const int slice = i >> 4;                  // 16 slices per batch
    const size_t gb = (size_t)b * NPX;
    const int start = slice * 7455, end = start + 7455;   // 6*19880/16

    for (int w = start + (int)threadIdx.x; w < end; w += 1024) {
        const int kind = w / 19880;            // 0:A1 1:A0 2:B1 3:B0 4:CD 5:CG
        const int cell = w - kind * 19880;
        const int row = cell / 71, c4 = (cell - row * 71) * 4;
        const int gy = row - 12;
        float4 v = make_float4(0.f, 0.f, 0.f, 0.f);
        if (kind < 2) {
            const float* sp = kind ? u0 : u1;
            if (gy >= 0 && gy < DIM) {
                #pragma unroll
                for (int k = 0; k < 4; ++k) {
                    const int gx = c4 + k - 12;
                    if (gx >= 0 && gx < DIM)
                        ((float*)&v)[k] = sp[gb + gy * DIM + gx];
                }
            }
        } else if (kind >= 4) {
            if (gy >= 0 && gy < DIM) {
                #pragma unroll
                for (int k = 0; k < 4; ++k) {
                    const int gx = c4 + k - 12;
                    if (gx >= 0 && gx < DIM) {
                        const float e = epsr[gb + gy * DIM + gx];
                        const float s = sigma[gb + gy * DIM + gx];
                        const float d = 1.f / (4.f * e + s);   // exact div once
                        ((float*)&v)[k] = (kind == 4) ? d : (4.f * e - s) * d;
                    }
                }
            }
        }
        float* dst = (kind == 0) ? A1 : (kind == 1) ? A0 : (kind == 2) ? B1
                   : (kind == 3) ? B0 : (kind == 4) ? CDp : CGp;
        *(float4*)&dst[(size_t)b * PBS + (size_t)row * PC + c4] = v;
    }
}

// One fused sub-step (col geometry identical to r10; rows for 32-row tile).
// Outputs on an absolute 4-col grid -> all LDS accesses aligned b128 with
// contiguous lanes. Edge pixels outside the logical region are computed but
// provably never consumed. Coefficients read from global (padded planes, L2).
template<int NB, int NG, int J0, int OFF>
__device__ __forceinline__ void substep(
    const float (*__restrict__ Fs)[LC], float (*__restrict__ Fd)[LC],
    const float* __restrict__ CDb, const float* __restrict__ CGb,  // block bases
    const float* __restrict__ eff, float ds, bool srcHere, int t)
{
    constexpr int SLOTS = NB * NG;
    if (t < SLOTS) {
        const int band = t / NG;               // compile-time divisor
        const int j    = J0 + (t - band * NG);
        const int pcol = 4 * j;                // physical col of 4 owned px
        const int yb   = OFF + 4 * band;       // first of 4 owned rows

        float a[4][4] = {{0,0,0,0},{0,0,0,0},{0,0,0,0},{0,0,0,0}};
        #pragma unroll
        for (int ky = 0; ky < 10; ++ky) {      // 10 rows feed 4 output rows
            const int row = yb - 3 + ky;
            const float4 q0 = *(const float4*)&Fs[row][pcol - 4];
            const float4 q1 = *(const float4*)&Fs[row][pcol];
            const float4 q2 = *(const float4*)&Fs[row][pcol + 4];
            const float v[12] = {q0.x,q0.y,q0.z,q0.w, q1.x,q1.y,q1.z,q1.w,
                                 q2.x,q2.y,q2.z,q2.w};
            #pragma unroll
            for (int o = 0; o < 4; ++o) {
                const int kh = ky - o;
                if (kh >= 0 && kh < 7) {
                    #pragma unroll
                    for (int kx = 0; kx < 7; ++kx) {
                        const float E = eff[kh * 7 + kx];   // uniform s_load
                        a[o][0] = fmaf(v[kx + 1], E, a[o][0]);
                        a[o][1] = fmaf(v[kx + 2], E, a[o][1]);
                        a[o][2] = fmaf(v[kx + 3], E, a[o][2]);
                        a[o][3] = fmaf(v[kx + 4], E, a[o][3]);
                    }
                }
            }
        }
        // epilogue: val = D1*conv + u1 + G*(u1-u0); u1/u0 from LDS (b128),
        // D1/G from global padded planes (coalesced f4, XCD-local L2)
        #pragma unroll
        for (int o = 0; o < 4; ++o) {
            const int row = yb + o;
            const float4 dq  = *(const float4*)&CDb[row * PC + pcol];
            const float4 gq  = *(const float4*)&CGb[row * PC + pcol];
            const float4 u1q = *(const float4*)&Fs[row][pcol];
            const float4 u0q = *(const float4*)&Fd[row][pcol];
            float4 r;
            r.x = fmaf(dq.x, a[o][0], fmaf(gq.x, u1q.x - u0q.x, u1q.x));
            r.y = fmaf(dq.y, a[o][1], fmaf(gq.y, u1q.y - u0q.y, u1q.y));
            r.z = fmaf(dq.z, a[o][2], fmaf(gq.z, u1q.z - u0q.z, u1q.z));
            r.w = fmaf(dq.w, a[o][3], fmaf(gq.w, u1q.w - u0q.w, u1q.w));
            if (srcHere && row == 12 && pcol == 16)        // px (128,128)
                r.x = fmaf(-dq.x, ds, r.x);
            *(float4*)&Fd[row][pcol] = r;
        }
    }
}

// 4 FDTD steps per launch. 512 blocks = 2/CU (46.4 KB LDS, 32 waves/CU):
// one block's staging/barriers hide under the other's compute.
// Block i -> XCD i&7, batch 2(i&7)+((i>>3)&1), tile i>>4 (4x8 of 64x32).
__global__ __launch_bounds__(1024) void fdtd4(
    const float* __restrict__ U1, const float* __restrict__ U0,   // padded
    const float* __restrict__ CDg, const float* __restrict__ CGg, // padded
    const float* __restrict__ eff, const float* __restrict__ src,
    float* __restrict__ NU1, int n1bs, int n1rs, int n1off,
    float* __restrict__ NU0, int sbase)
{
    __shared__ __align__(16) float F[2][LR][LC];     // 46.4 KB

    const int t = threadIdx.x;
    const int i = blockIdx.x;
    const int b    = 2 * (i & 7) + ((i >> 3) & 1);
    const int tile = i >> 4;                   // 0..31
    const int bx = tile & 3, ty = tile >> 2;   // 64-col x 32-row tiles
    const bool srcHere = (bx == 2 && ty == 4);
    const size_t pbF = (size_t)b * PBS;
    const size_t tofs = (size_t)(ty * 32) * PC + bx * 64;  // region(0,0) in plane

    // ---- stage fields: 2 arrays x 56 rows x 22 f4 (region rows 0..55) ----
    {
        const float* s1 = U1 + pbF + tofs;
        const float* s0 = U0 + pbF + tofs;
        #pragma unroll
        for (int rep = 0; rep < 3; ++rep) {
            const int idx = t + rep * 1024;
            if (idx < 2 * 1232) {
                const int arr = idx >= 1232 ? 1 : 0;
                const int j2  = idx - arr * 1232;
                const int row = j2 / 22, c4 = (j2 - row * 22) * 4;
                const float4 v = *(const float4*)
                    &(arr ? s0 : s1)[(size_t)row * PC + c4];
                *(float4*)&F[arr][row][4 + c4] = v;
            }
        }
    }
    __syncthreads();

    // coefficient block bases: region(row, LDS col pcol) -> base + row*PC + pcol
    const float* CDb = CDg + pbF + tofs - 4;
    const float* CGb = CGg + pbF + tofs - 4;

    const float ds0 = src[2 * sbase]     - src[2 * sbase + 1];
    const float ds1 = src[2 * sbase + 2] - src[2 * sbase + 3];
    const float ds2 = src[2 * sbase + 4] - src[2 * sbase + 5];
    const float ds3 = src[2 * sbase + 6] - src[2 * sbase + 7];

    substep<13, 22, 1,  3>(F[0], F[1], CDb, CGb, eff, ds0, srcHere, t); __syncthreads();
    substep<11, 20, 2,  6>(F[1], F[0], CDb, CGb, eff, ds1, srcHere, t); __syncthreads();
    substep<10, 18, 3,  9>(F[0], F[1], CDb, CGb, eff, ds2, srcHere, t); __syncthreads();
    substep< 8, 16, 4, 12>(F[1], F[0], CDb, CGb, eff, ds3, srcHere, t); __syncthreads();

    // ---- store clean 32x64 interior: F0 = u_{s+4}, F1 = u_{s+3} ----
    if (t < 512) {
        const int row = t >> 4, c = (t & 15) * 4;
        const int gy = ty * 32 + row, gx = bx * 64 + c;
        const float4 o1 = *(const float4*)&F[0][12 + row][16 + c];
        const float4 o0 = *(const float4*)&F[1][12 + row][16 + c];
        *(float4*)&NU1[(size_t)b * n1bs + (size_t)(gy + n1off) * n1rs + gx + n1off] = o1;
        *(float4*)&NU0[pbF + (size_t)(gy + 12) * PC + gx + 12] = o0;
    }
}

extern "C" void kernel_launch(void* const* d_in, const int* in_sizes, int n_in,
                              void* d_out, int out_size, void* d_ws, size_t ws_size,
                              hipStream_t stream) {
    (void)in_sizes; (void)n_in; (void)out_size; (void)ws_size;

    const float* u1    = (const float*)d_in[0];
    const float* u0    = (const float*)d_in[1];
    const float* epsr  = (const float*)d_in[2];
    const float* sigma = (const float*)d_in[3];
    const float* fdk   = (const float*)d_in[4];
    const float* cw    = (const float*)d_in[5];
    const float* src   = (const float*)d_in[6];

    float* eff = (float*)d_ws;          // 64 floats, keeps arrays 16B-aligned
    float* A1  = eff + 64;
    float* A0  = A1 + NPAD;
    float* B1  = A0 + NPAD;
    float* B0  = B1 + NPAD;
    float* CDg = B0 + NPAD;
    float* CGg = CDg + NPAD;            // 6 planes x 5.1 MB ~= 30.5 MB ws

    prep_eff<<<1, 64, 0, stream>>>(fdk, cw, eff);
    prologue<<<256, 1024, 0, stream>>>(u1, u0, epsr, sigma, A1, A0, B1, B0, CDg, CGg);

    for (int j = 0; j < 8; ++j) {       // 8 x 4 fused steps = 32
        const float* cu1 = (j & 1) ? B1 : A1;
        const float* cu0 = (j & 1) ? B0 : A0;
        float* n1 = (j & 1) ? A1 : B1;
        float* n0 = (j & 1) ? A0 : B0;
        int bs = PBS, rs = PC, off = 12;
        if (j == 7) { n1 = (float*)d_out; bs = NPX; rs = DIM; off = 0; }
        fdtd4<<<512, 1024, 0, stream>>>(cu1, cu0, CDg, CGg, eff, src,
                                        n1, bs, rs, off, n0, 4 * j);
    }
}

// Round 12
// 251.590 us; speedup vs baseline: 1.1455x; 1.1455x over previous
//
#include <hip/hip_runtime.h>

#define DIM   256
#define BATCH 16
#define NPX   (DIM*DIM)

// all padded global arrays share one layout: [280 rows][284 cols],
// px(gy,gx) at (gy+12, gx+12); zeros outside the image.
#define PR   280
#define PC   284
#define PBS  (PR*PC)
#define NPAD ((size_t)BATCH*PBS)

// LDS: fields only, [2][58][100] = 46.4 KB -> 2 blocks/CU (92.8 KB/CU).
// Block tile = 32 rows x 64 cols, halo 12 -> region 56 x 88 (+2 overreach rows,
// +4-col pads). Coefficients are read from global planes (XCD-local L2),
// hoisted into registers before the conv (512-thread block -> 128-VGPR cap).
#define LR 58
#define LC 100

// Collapse the 14 used fd_kernels into one effective 7x7 kernel.
__global__ void prep_eff(const float* __restrict__ fdk,
                         const float* __restrict__ cw,
                         float* __restrict__ eff) {
    int t = threadIdx.x;
    if (t < 49) {
        float s = 0.f;
        #pragma unroll
        for (int c = 1; c < 15; ++c)
            s += fdk[c * 49 + t] * cw[c - 1];
        eff[t] = s;
    }
}

// XCD-aware streaming prologue (unchanged): block i -> batch 2(i&7)+((i>>3)&1).
__global__ __launch_bounds__(1024) void prologue(
    const float* __restrict__ u1, const float* __restrict__ u0,
    const float* __restrict__ epsr, const float* __restrict__ sigma,
    float* __restrict__ A1, float* __restrict__ A0,
    float* __restrict__ B1, float* __restrict__ B0,
    float* __restrict__ CDp, float* __restrict__ CGp)
{
    const int i = blockIdx.x;
    const int b = 2 * (i & 7) + ((i >> 3) & 1);
    const int slice = i >> 4;                  // 16 slices per batch
    const size_t gb = (size_t)b * NPX;
    const int start = slice * 7455, end = start + 7455;   // 6*19880/16

    for (int w = start + (int)threadIdx.x; w < end; w += 1024) {
        const int kind = w / 19880;            // 0:A1 1:A0 2:B1 3:B0 4:CD 5:CG
        const int cell = w - kind * 19880;
        const int row = cell / 71, c4 = (cell - row * 71) * 4;
        const int gy = row - 12;
        float4 v = make_float4(0.f, 0.f, 0.f, 0.f);
        if (kind < 2) {
            const float* sp = kind ? u0 : u1;
            if (gy >= 0 && gy < DIM) {
                #pragma unroll
                for (int k = 0; k < 4; ++k) {
                    const int gx = c4 + k - 12;
                    if (gx >= 0 && gx < DIM)
                        ((float*)&v)[k] = sp[gb + gy * DIM + gx];
                }
            }
        } else if (kind >= 4) {
            if (gy >= 0 && gy < DIM) {
                #pragma unroll
                for (int k = 0; k < 4; ++k) {
                    const int gx = c4 + k - 12;
                    if (gx >= 0 && gx < DIM) {
                        const float e = epsr[gb + gy * DIM + gx];
                        const float s = sigma[gb + gy * DIM + gx];
                        const float d = 1.f / (4.f * e + s);   // exact div once
                        ((float*)&v)[k] = (kind == 4) ? d : (4.f * e - s) * d;
                    }
                }
            }
        }
        float* dst = (kind == 0) ? A1 : (kind == 1) ? A0 : (kind == 2) ? B1
                   : (kind == 3) ? B0 : (kind == 4) ? CDp : CGp;
        *(float4*)&dst[(size_t)b * PBS + (size_t)row * PC + c4] = v;
    }
}

// One fused sub-step (r11 geometry, proven safe: garbage edge pixels are
// provably never consumed). Changes vs r11: coeff loads HOISTED above the
// conv (hidden under ~1600 cy of FMA), u1 centers CAPTURED during the conv
// (saves 4 LDS b128/slot). Needs ~90 VGPRs -> 512-thread block (cap 128).
template<int NB, int NG, int J0, int OFF>
__device__ __forceinline__ void substep(
    const float (*__restrict__ Fs)[LC], float (*__restrict__ Fd)[LC],
    const float* __restrict__ CDb, const float* __restrict__ CGb,  // block bases
    const float* __restrict__ eff, float ds, bool srcHere, int t)
{
    constexpr int SLOTS = NB * NG;
    if (t < SLOTS) {
        const int band = t / NG;               // compile-time divisor
        const int j    = J0 + (t - band * NG);
        const int pcol = 4 * j;                // physical col of 4 owned px
        const int yb   = OFF + 4 * band;       // first of 4 owned rows

        // hoisted coefficient loads (global padded planes, XCD-local L2)
        float4 dq4[4], gq4[4];
        #pragma unroll
        for (int o = 0; o < 4; ++o) {
            dq4[o] = *(const float4*)&CDb[(yb + o) * PC + pcol];
            gq4[o] = *(const float4*)&CGb[(yb + o) * PC + pcol];
        }

        float a[4][4] = {{0,0,0,0},{0,0,0,0},{0,0,0,0},{0,0,0,0}};
        float4 c4[4];                          // captured u1 centers
        #pragma unroll
        for (int ky = 0; ky < 10; ++ky) {      // 10 rows feed 4 output rows
            const int row = yb - 3 + ky;
            const float4 q0 = *(const float4*)&Fs[row][pcol - 4];
            const float4 q1 = *(const float4*)&Fs[row][pcol];
            const float4 q2 = *(const float4*)&Fs[row][pcol + 4];
            if (ky >= 3 && ky <= 6) c4[ky - 3] = q1;
            const float v[12] = {q0.x,q0.y,q0.z,q0.w, q1.x,q1.y,q1.z,q1.w,
                                 q2.x,q2.y,q2.z,q2.w};
            #pragma unroll
            for (int o = 0; o < 4; ++o) {
                const int kh = ky - o;
                if (kh >= 0 && kh < 7) {
                    #pragma unroll
                    for (int kx = 0; kx < 7; ++kx) {
                        const float E = eff[kh * 7 + kx];   // uniform s_load
                        a[o][0] = fmaf(v[kx + 1], E, a[o][0]);
                        a[o][1] = fmaf(v[kx + 2], E, a[o][1]);
                        a[o][2] = fmaf(v[kx + 3], E, a[o][2]);
                        a[o][3] = fmaf(v[kx + 4], E, a[o][3]);
                    }
                }
            }
        }
        // epilogue: val = D1*conv + u1 + G*(u1-u0); u0 from LDS (b128)
        #pragma unroll
        for (int o = 0; o < 4; ++o) {
            const int row = yb + o;
            const float4 u0q = *(const float4*)&Fd[row][pcol];
            float4 r;
            r.x = fmaf(dq4[o].x, a[o][0], fmaf(gq4[o].x, c4[o].x - u0q.x, c4[o].x));
            r.y = fmaf(dq4[o].y, a[o][1], fmaf(gq4[o].y, c4[o].y - u0q.y, c4[o].y));
            r.z = fmaf(dq4[o].z, a[o][2], fmaf(gq4[o].z, c4[o].z - u0q.z, c4[o].z));
            r.w = fmaf(dq4[o].w, a[o][3], fmaf(gq4[o].w, c4[o].w - u0q.w, c4[o].w));
            if (srcHere && row == 12 && pcol == 16)        // px (128,128)
                r.x = fmaf(-dq4[o].x, ds, r.x);
            *(float4*)&Fd[row][pcol] = r;
        }
    }
}

// 4 FDTD steps per launch. 512 blocks x 512 threads = 2 blocks/CU:
// TWO independent barrier domains per CU -> one block's staging/barrier
// drain overlaps the other's compute. __launch_bounds__(512,4): 4 waves/EU
// min (= 2 blocks/CU) -> VGPR cap 128, room to hoist coeffs + capture u1.
// Block i -> XCD i&7, batch 2(i&7)+((i>>3)&1), tile i>>4 (4x8 of 64x32).
__global__ __launch_bounds__(512, 4) void fdtd4(
    const float* __restrict__ U1, const float* __restrict__ U0,   // padded
    const float* __restrict__ CDg, const float* __restrict__ CGg, // padded
    const float* __restrict__ eff, const float* __restrict__ src,
    float* __restrict__ NU1, int n1bs, int n1rs, int n1off,
    float* __restrict__ NU0, int sbase)
{
    __shared__ __align__(16) float F[2][LR][LC];     // 46.4 KB

    const int t = threadIdx.x;
    const int i = blockIdx.x;
    const int b    = 2 * (i & 7) + ((i >> 3) & 1);
    const int tile = i >> 4;                   // 0..31
    const int bx = tile & 3, ty = tile >> 2;   // 64-col x 32-row tiles
    const bool srcHere = (bx == 2 && ty == 4);
    const size_t pbF = (size_t)b * PBS;
    const size_t tofs = (size_t)(ty * 32) * PC + bx * 64;  // region(0,0) in plane

    // ---- stage fields: 2 arrays x 56 rows x 22 f4 (region rows 0..55) ----
    {
        const float* s1 = U1 + pbF + tofs;
        const float* s0 = U0 + pbF + tofs;
        #pragma unroll
        for (int rep = 0; rep < 5; ++rep) {
            const int idx = t + rep * 512;
            if (idx < 2 * 1232) {
                const int arr = idx >= 1232 ? 1 : 0;
                const int j2  = idx - arr * 1232;
                const int row = j2 / 22, c4 = (j2 - row * 22) * 4;
                const float4 v = *(const float4*)
                    &(arr ? s0 : s1)[(size_t)row * PC + c4];
                *(float4*)&F[arr][row][4 + c4] = v;
            }
        }
    }
    __syncthreads();

    // coefficient block bases: region(row, LDS col pcol) -> base + row*PC + pcol
    const float* CDb = CDg + pbF + tofs - 4;
    const float* CGb = CGg + pbF + tofs - 4;

    const float ds0 = src[2 * sbase]     - src[2 * sbase + 1];
    const float ds1 = src[2 * sbase + 2] - src[2 * sbase + 3];
    const float ds2 = src[2 * sbase + 4] - src[2 * sbase + 5];
    const float ds3 = src[2 * sbase + 6] - src[2 * sbase + 7];

    substep<13, 22, 1,  3>(F[0], F[1], CDb, CGb, eff, ds0, srcHere, t); __syncthreads();
    substep<11, 20, 2,  6>(F[1], F[0], CDb, CGb, eff, ds1, srcHere, t); __syncthreads();
    substep<10, 18, 3,  9>(F[0], F[1], CDb, CGb, eff, ds2, srcHere, t); __syncthreads();
    substep< 8, 16, 4, 12>(F[1], F[0], CDb, CGb, eff, ds3, srcHere, t); __syncthreads();

    // ---- store clean 32x64 interior: F0 = u_{s+4}, F1 = u_{s+3} ----
    {
        const int row = t >> 4, c = (t & 15) * 4;   // 512 threads = 32x16 f4
        const int gy = ty * 32 + row, gx = bx * 64 + c;
        const float4 o1 = *(const float4*)&F[0][12 + row][16 + c];
        const float4 o0 = *(const float4*)&F[1][12 + row][16 + c];
        *(float4*)&NU1[(size_t)b * n1bs + (size_t)(gy + n1off) * n1rs + gx + n1off] = o1;
        *(float4*)&NU0[pbF + (size_t)(gy + 12) * PC + gx + 12] = o0;
    }
}

extern "C" void kernel_launch(void* const* d_in, const int* in_sizes, int n_in,
                              void* d_out, int out_size, void* d_ws, size_t ws_size,
                              hipStream_t stream) {
    (void)in_sizes; (void)n_in; (void)out_size; (void)ws_size;

    const float* u1    = (const float*)d_in[0];
    const float* u0    = (const float*)d_in[1];
    const float* epsr  = (const float*)d_in[2];
    const float* sigma = (const float*)d_in[3];
    const float* fdk   = (const float*)d_in[4];
    const float* cw    = (const float*)d_in[5];
    const float* src   = (const float*)d_in[6];

    float* eff = (float*)d_ws;          // 64 floats, keeps arrays 16B-aligned
    float* A1  = eff + 64;
    float* A0  = A1 + NPAD;
    float* B1  = A0 + NPAD;
    float* B0  = B1 + NPAD;
    float* CDg = B0 + NPAD;
    float* CGg = CDg + NPAD;            // 6 planes x 5.1 MB ~= 30.5 MB ws

    prep_eff<<<1, 64, 0, stream>>>(fdk, cw, eff);
    prologue<<<256, 1024, 0, stream>>>(u1, u0, epsr, sigma, A1, A0, B1, B0, CDg, CGg);

    for (int j = 0; j < 8; ++j) {       // 8 x 4 fused steps = 32
        const float* cu1 = (j & 1) ? B1 : A1;
        const float* cu0 = (j & 1) ? B0 : A0;
        float* n1 = (j & 1) ? A1 : B1;
        float* n0 = (j & 1) ? A0 : B0;
        int bs = PBS, rs = PC, off = 12;
        if (j == 7) { n1 = (float*)d_out; bs = NPX; rs = DIM; off = 0; }
        fdtd4<<<512, 512, 0, stream>>>(cu1, cu0, CDg, CGg, eff, src,
                                       n1, bs, rs, off, n0, 4 * j);
    }
}